// Round 1
// baseline (4384.847 us; speedup 1.0000x reference)
//
#include <hip/hip_runtime.h>

#define B 64
#define S 128
#define T 64
#define H 512
#define E 256
#define V 10000
#define H2 1024      // 2H
#define G4 2048      // 4H
#define KX 1536      // ctx(1024)+h(512) gate GEMM K
#define KP 1792      // E + H + 2H pre concat K
#define VP 10112     // padded V = 79*128
#define NROW 4096    // B*T

typedef unsigned short u16;
typedef __attribute__((ext_vector_type(8))) short bf16x8;
typedef __attribute__((ext_vector_type(4))) float floatx4;

__device__ inline float b2f(u16 h){
  union { unsigned int u; float f; } v; v.u = ((unsigned int)h) << 16; return v.f;
}
__device__ inline u16 f2b(float f){
  union { unsigned int u; float f; } v; v.f = f;
  unsigned int r = v.u + 0x7FFFu + ((v.u >> 16) & 1u);
  return (u16)(r >> 16);
}
__device__ inline float sigf(float x){ return 1.f/(1.f+__expf(-x)); }
__device__ inline float tanh_fast(float x){ float e=__expf(2.f*x); return 1.f - 2.f/(e+1.f); }

// ---------------- prep kernels ----------------
__global__ void k_cast(const float* __restrict__ src, u16* __restrict__ dst, int n){
  int i = blockIdx.x*256 + threadIdx.x;
  if (i < n) dst[i] = f2b(src[i]);
}
// dst[c*R+r] = src[r*C+c]
__global__ void k_transpose_cast(const float* __restrict__ src, u16* __restrict__ dst, int R, int C){
  int i = blockIdx.x*256 + threadIdx.x;
  if (i < R*C){ int r = i / C, c = i % C; dst[(size_t)c*R + r] = f2b(src[i]); }
}
// Wch[gp][k]: gp = j*4+gate (permuted), k<1024 -> W_ih[g][E+k], else W_hh[g][k-1024]
__global__ void k_wch(const float* __restrict__ wih, const float* __restrict__ whh, u16* __restrict__ o){
  int i = blockIdx.x*256 + threadIdx.x;
  if (i < G4*KX){
    int gp = i / KX, k = i % KX;
    int j = gp >> 2, gate = gp & 3, g = gate*H + j;
    float v = (k < H2) ? wih[(size_t)g*(E+H2) + E + k] : whh[(size_t)g*H + (k - H2)];
    o[i] = f2b(v);
  }
}
__global__ void k_wihe(const float* __restrict__ wih, u16* __restrict__ o){
  int i = blockIdx.x*256 + threadIdx.x;
  if (i < G4*E){
    int gp = i / E, e = i % E;
    int j = gp >> 2, gate = gp & 3, g = gate*H + j;
    o[i] = f2b(wih[(size_t)g*(E+H2) + e]);
  }
}
// WgT[v][k] = Wgen[k][v], zero-padded rows v>=V
__global__ void k_wgt(const float* __restrict__ wg, u16* __restrict__ o){
  int i = blockIdx.x*256 + threadIdx.x;
  if (i < VP*H){
    int v = i / H, k = i % H;
    o[i] = (v < V) ? f2b(wg[(size_t)k*V + v]) : (u16)0;
  }
}
__global__ void k_bias(const float* __restrict__ bi, const float* __restrict__ bh, float* __restrict__ o){
  int i = blockIdx.x*256 + threadIdx.x;
  if (i < G4){
    int j = i >> 2, gate = i & 3, g = gate*H + j;
    o[i] = bi[g] + bh[g];
  }
}
// emb gather into cat_pre[:, 0:E]
__global__ void k_emb(const int* __restrict__ trg, const float* __restrict__ emb, u16* __restrict__ catp){
  int i = blockIdx.x*256 + threadIdx.x;
  if (i < NROW*E){
    int row = i >> 8, e = i & 255;
    int tok = trg[row];
    catp[(size_t)row*KP + e] = f2b(emb[(size_t)tok*E + e]);
  }
}
__global__ void k_init(const float* __restrict__ h0, const float* __restrict__ c0,
                       u16* __restrict__ xg0, float* __restrict__ cb0){
  int i = blockIdx.x*256 + threadIdx.x;
  if (i < B*H){
    int b = i >> 9, j = i & 511;
    xg0[b*KX + H2 + j] = f2b(h0[i]);
    cb0[i] = c0[i];
  }
}
__global__ void k_lse(const float* __restrict__ sep, float* __restrict__ lse){
  int r = blockIdx.x*256 + threadIdx.x;
  if (r < NROW){
    float s = 0.f;
    for (int i=0;i<79;i++) s += sep[(size_t)r*80 + i];
    lse[r] = logf(s);
  }
}
__global__ void k_fin(const float* __restrict__ hf, const float* __restrict__ cf, float* __restrict__ out){
  int i = blockIdx.x*256 + threadIdx.x;
  if (i < B*H){
    out[(size_t)B*V*T + i] = hf[i];
    out[(size_t)B*V*T + B*H + i] = cf[i];
  }
}

// ---------------- MFMA GEMM: C[row,col] = sum_k A[row,k]*BT[col,k] ----------------
// rows tiled 64 (4 waves x 16), cols tiled TN. 256 threads.
// EPI 0: store bf16 C. EPI 1: LSTM pointwise. EPI 2: sum-exp partials. EPI 3: out write with lse.
template<int TN, int EPI>
__global__ __launch_bounds__(256) void gemm_bf16(
    const u16* __restrict__ A, int lda,
    const u16* __restrict__ BT, int ldb,
    int K,
    u16* outb, int ldc,
    const u16* gemb, const float* bias, const float* cin, float* cout,
    float* hfin, u16* xgh, u16* cph, int t,
    float* sep,
    float* outp, const float* lse)
{
  constexpr int NSUB = TN/16;
  __shared__ u16 sA[64*32];
  __shared__ u16 sB[TN*32];
  __shared__ float Cx[(EPI==1) ? 64*65 : ((EPI==3) ? 128*65 : 1)];
  __shared__ float lseb[(EPI==3)?64:1];

  const int tid = threadIdx.x;
  const int lane = tid & 63;
  const int wv = tid >> 6;
  const int row0 = blockIdx.x * 64;
  const int n0 = blockIdx.y * TN;

  floatx4 acc[NSUB];
  #pragma unroll
  for (int s=0;s<NSUB;s++) acc[s] = (floatx4){0.f,0.f,0.f,0.f};

  const int ar = tid >> 2;
  const int ac = (tid & 3) * 8;

  for (int k0 = 0; k0 < K; k0 += 32){
    *(bf16x8*)&sA[ar*32 + ac] = *(const bf16x8*)(A + (size_t)(row0+ar)*lda + k0 + ac);
    #pragma unroll
    for (int i=0;i<TN/64;i++){
      int r2 = i*64 + ar;
      *(bf16x8*)&sB[r2*32 + ac] = *(const bf16x8*)(BT + (size_t)(n0+r2)*ldb + k0 + ac);
    }
    __syncthreads();
    bf16x8 af = *(const bf16x8*)&sA[(16*wv + (lane&15))*32 + (lane>>4)*8];
    #pragma unroll
    for (int s=0;s<NSUB;s++){
      bf16x8 bfv = *(const bf16x8*)&sB[(16*s + (lane&15))*32 + (lane>>4)*8];
      acc[s] = __builtin_amdgcn_mfma_f32_16x16x32_bf16(af, bfv, acc[s], 0, 0, 0);
    }
    __syncthreads();
  }

  if constexpr (EPI == 0){
    #pragma unroll
    for (int s=0;s<NSUB;s++)
      #pragma unroll
      for (int r=0;r<4;r++){
        int row = row0 + 16*wv + ((lane>>4)<<2) + r;
        int col = n0 + 16*s + (lane&15);
        outb[(size_t)row*ldc + col] = f2b(acc[s][r]);
      }
  }
  if constexpr (EPI == 1){
    #pragma unroll
    for (int s=0;s<NSUB;s++)
      #pragma unroll
      for (int r=0;r<4;r++){
        int rl = 16*wv + ((lane>>4)<<2) + r;
        int cl = 16*s + (lane&15);
        Cx[rl*65 + cl] = acc[s][r];
      }
    __syncthreads();
    for (int idx = tid; idx < 64*16; idx += 256){
      int b = idx >> 4, jl = idx & 15;
      int gp = n0 + jl*4;
      int j = (n0>>2) + jl;
      size_t grow = (size_t)(b*T + t)*G4 + gp;
      float gi = Cx[b*65 + jl*4+0] + b2f(gemb[grow+0]) + bias[gp+0];
      float gf = Cx[b*65 + jl*4+1] + b2f(gemb[grow+1]) + bias[gp+1];
      float gg = Cx[b*65 + jl*4+2] + b2f(gemb[grow+2]) + bias[gp+2];
      float go = Cx[b*65 + jl*4+3] + b2f(gemb[grow+3]) + bias[gp+3];
      float cold = cin[b*H + j];
      float cn = sigf(gf)*cold + sigf(gi)*tanhf(gg);
      float hn = sigf(go)*tanhf(cn);
      cout[b*H + j] = cn;
      hfin[b*H + j] = hn;
      u16 hb = f2b(hn);
      xgh[b*KX + H2 + j] = hb;
      cph[(size_t)(b*T + t)*KP + E + j] = hb;
    }
  }
  if constexpr (EPI == 2){
    float sr[4] = {0.f,0.f,0.f,0.f};
    #pragma unroll
    for (int s=0;s<NSUB;s++){
      int col = n0 + 16*s + (lane&15);
      if (col < V){
        #pragma unroll
        for (int r=0;r<4;r++) sr[r] += __expf(acc[s][r]);
      }
    }
    #pragma unroll
    for (int r=0;r<4;r++){
      float v = sr[r];
      v += __shfl_xor(v,1); v += __shfl_xor(v,2); v += __shfl_xor(v,4); v += __shfl_xor(v,8);
      sr[r] = v;
    }
    if ((lane&15)==0){
      #pragma unroll
      for (int r=0;r<4;r++){
        int row = row0 + 16*wv + ((lane>>4)<<2) + r;
        sep[(size_t)row*80 + blockIdx.y] = sr[r];
      }
    }
  }
  if constexpr (EPI == 3){
    #pragma unroll
    for (int s=0;s<NSUB;s++)
      #pragma unroll
      for (int r=0;r<4;r++){
        int rl = 16*wv + ((lane>>4)<<2) + r;   // t within batch row-block
        int cl = 16*s + (lane&15);             // v local
        Cx[cl*65 + rl] = acc[s][r];
      }
    if (tid < 64) lseb[tid] = lse[row0 + tid];
    __syncthreads();
    int b = blockIdx.x;
    for (int idx = tid; idx < TN*16; idx += 256){
      int vl = idx >> 4, q4 = idx & 15;
      int v = n0 + vl;
      if (v < V){
        floatx4 o;
        o[0] = Cx[vl*65 + q4*4+0] - lseb[q4*4+0];
        o[1] = Cx[vl*65 + q4*4+1] - lseb[q4*4+1];
        o[2] = Cx[vl*65 + q4*4+2] - lseb[q4*4+2];
        o[3] = Cx[vl*65 + q4*4+3] - lseb[q4*4+3];
        *(floatx4*)&outp[((size_t)b*V + v)*T + q4*4] = o;
      }
    }
  }
}

// ---------------- per-step attention (one block per batch element) ----------------
__global__ __launch_bounds__(512) void attn_step(
    u16* __restrict__ xg,          // slot t&1: read h at [b][H2..], write ctx at [b][0..H2)
    const u16* __restrict__ pk,    // [B*S][H] bf16
    const u16* __restrict__ encb,  // [B*S][H2] bf16
    const float* __restrict__ we,
    const int* __restrict__ lens,
    const u16* __restrict__ wqT,   // [H][H]: wqT[j][k] = Wquery[k][j]
    u16* __restrict__ cph,         // cat_pre
    int t)
{
  __shared__ float hq[H], qv[H], wel[H];
  __shared__ float ep[512];
  __shared__ float ev[S], al[S];
  __shared__ float red[S];
  __shared__ float smax, ssum;
  const int tid = threadIdx.x;
  const int b = blockIdx.x;

  hq[tid] = b2f(xg[b*KX + H2 + tid]);
  wel[tid] = we[tid];
  __syncthreads();

  // q[j] = sum_k h[k] * Wquery[k][j]
  {
    const u16* wr = wqT + (size_t)tid*H;
    float a0 = 0.f;
    for (int k=0;k<H;k+=8){
      bf16x8 w8 = *(const bf16x8*)(wr + k);
      #pragma unroll
      for (int i=0;i<8;i++) a0 += hq[k+i]*b2f((u16)w8[i]);
    }
    qv[tid] = a0;
  }
  __syncthreads();

  // energies: 4 threads per s, K-range 128 each
  {
    int s = tid >> 2, part = tid & 3;
    const u16* pr = pk + (size_t)(b*S + s)*H + part*128;
    float a0 = 0.f;
    for (int k=0;k<128;k+=8){
      bf16x8 p8 = *(const bf16x8*)(pr + k);
      int kk = part*128 + k;
      #pragma unroll
      for (int i=0;i<8;i++){
        float x = qv[kk+i] + b2f((u16)p8[i]);
        a0 += tanh_fast(x) * wel[kk+i];
      }
    }
    ep[tid] = a0;
  }
  __syncthreads();
  if (tid < S){
    float e = ep[tid*4] + ep[tid*4+1] + ep[tid*4+2] + ep[tid*4+3];
    ev[tid] = (tid < lens[b]) ? e : -1e30f;
    red[tid] = ev[tid];
  }
  __syncthreads();
  for (int w2=64; w2>=1; w2>>=1){
    if (tid < w2) red[tid] = fmaxf(red[tid], red[tid+w2]);
    __syncthreads();
  }
  if (tid==0) smax = red[0];
  __syncthreads();
  if (tid < S){
    float pexp = __expf(ev[tid]-smax);
    al[tid] = pexp;
    red[tid] = pexp;
  }
  __syncthreads();
  for (int w2=64; w2>=1; w2>>=1){
    if (tid < w2) red[tid] += red[tid+w2];
    __syncthreads();
  }
  if (tid==0) ssum = 1.f/red[0];
  __syncthreads();

  // ctx: 2 d per thread
  {
    float c0=0.f, c1=0.f;
    int d = tid*2;
    const u16* er = encb + (size_t)(b*S)*H2 + d;
    for (int s=0;s<S;s++){
      float a = al[s];
      unsigned int u = *(const unsigned int*)(er + (size_t)s*H2);
      c0 += a * b2f((u16)(u & 0xFFFFu));
      c1 += a * b2f((u16)(u >> 16));
    }
    c0 *= ssum; c1 *= ssum;
    u16 h0b = f2b(c0), h1b = f2b(c1);
    xg[b*KX + d] = h0b; xg[b*KX + d + 1] = h1b;
    size_t cr = (size_t)(b*T + t)*KP + E + H + d;
    cph[cr] = h0b; cph[cr+1] = h1b;
  }
}

static inline int cdiv(int a, int b){ return (a + b - 1) / b; }

extern "C" void kernel_launch(void* const* d_in, const int* in_sizes, int n_in,
                              void* d_out, int out_size, void* d_ws, size_t ws_size,
                              hipStream_t stream)
{
  (void)in_sizes; (void)n_in; (void)out_size; (void)ws_size;
  const int*   trg  = (const int*)d_in[0];
  const float* enc  = (const float*)d_in[1];
  const int*   lens = (const int*)d_in[2];
  const float* h0   = (const float*)d_in[3];
  const float* c0   = (const float*)d_in[4];
  const float* embt = (const float*)d_in[5];
  const float* wkey = (const float*)d_in[6];
  const float* wqry = (const float*)d_in[7];
  const float* we   = (const float*)d_in[8];
  const float* wih  = (const float*)d_in[9];
  const float* whh  = (const float*)d_in[10];
  const float* bi   = (const float*)d_in[11];
  const float* bh   = (const float*)d_in[12];
  const float* wpre = (const float*)d_in[13];
  const float* wgen = (const float*)d_in[14];
  float* out = (float*)d_out;

  char* p = (char*)d_ws;
  auto carve = [&](size_t bytes)->char*{ char* r = p; p += (bytes + 255) & ~(size_t)255; return r; };
  u16*   encb  = (u16*)  carve((size_t)B*S*H2*2);
  u16*   pkb   = (u16*)  carve((size_t)B*S*H*2);
  u16*   catp  = (u16*)  carve((size_t)NROW*KP*2);
  u16*   gembb = (u16*)  carve((size_t)NROW*G4*2);
  u16*   preb  = (u16*)  carve((size_t)NROW*H*2);
  u16*   wgt   = (u16*)  carve((size_t)VP*H*2);
  u16*   wch   = (u16*)  carve((size_t)G4*KX*2);
  u16*   wihe  = (u16*)  carve((size_t)G4*E*2);
  u16*   wkeyT = (u16*)  carve((size_t)H*H2*2);
  u16*   wqT   = (u16*)  carve((size_t)H*H*2);
  u16*   wpreT = (u16*)  carve((size_t)H*KP*2);
  u16*   xg    = (u16*)  carve((size_t)2*B*KX*2);
  float* cbuf  = (float*)carve((size_t)2*B*H*4);
  float* hfin  = (float*)carve((size_t)B*H*4);
  float* biasp = (float*)carve((size_t)G4*4);
  float* sep   = (float*)carve((size_t)NROW*80*4);
  float* lse   = (float*)carve((size_t)NROW*4);

  // ---- prep ----
  k_cast<<<cdiv(B*S*H2,256),256,0,stream>>>(enc, encb, B*S*H2);
  k_transpose_cast<<<cdiv(H2*H,256),256,0,stream>>>(wkey, wkeyT, H2, H);
  k_transpose_cast<<<cdiv(H*H,256),256,0,stream>>>(wqry, wqT, H, H);
  k_transpose_cast<<<cdiv(KP*H,256),256,0,stream>>>(wpre, wpreT, KP, H);
  k_wch<<<cdiv(G4*KX,256),256,0,stream>>>(wih, whh, wch);
  k_wihe<<<cdiv(G4*E,256),256,0,stream>>>(wih, wihe);
  k_wgt<<<cdiv(VP*H,256),256,0,stream>>>(wgen, wgt);
  k_bias<<<cdiv(G4,256),256,0,stream>>>(bi, bh, biasp);
  k_emb<<<cdiv(NROW*E,256),256,0,stream>>>(trg, embt, catp);
  k_init<<<cdiv(B*H,256),256,0,stream>>>(h0, c0, xg, cbuf);

  // proj_key = enc @ Wkey  -> pk bf16 [B*S][H]
  gemm_bf16<64,0><<<dim3(B*S/64, H/64),256,0,stream>>>(
      encb, H2, wkeyT, H2, H2, pkb, H,
      nullptr,nullptr,nullptr,nullptr,nullptr,nullptr,nullptr,0,nullptr,nullptr,nullptr);
  // Gemb = emb @ W_ih[:, :E].T (permuted cols) -> bf16 [NROW][G4]
  gemm_bf16<64,0><<<dim3(NROW/64, G4/64),256,0,stream>>>(
      catp, KP, wihe, E, E, gembb, G4,
      nullptr,nullptr,nullptr,nullptr,nullptr,nullptr,nullptr,0,nullptr,nullptr,nullptr);

  // ---- recurrence ----
  for (int t=0; t<T; t++){
    u16* xgc = xg + (size_t)(t&1)*B*KX;
    u16* xgn = xg + (size_t)((t+1)&1)*B*KX;
    float* cin_  = cbuf + (size_t)(t&1)*B*H;
    float* cout_ = cbuf + (size_t)((t+1)&1)*B*H;
    attn_step<<<B,512,0,stream>>>(xgc, pkb, encb, we, lens, wqT, catp, t);
    gemm_bf16<64,1><<<dim3(1, G4/64),256,0,stream>>>(
        xgc, KX, wch, KX, KX, nullptr, 0,
        gembb, biasp, cin_, cout_, hfin, xgn, catp, t, nullptr, nullptr, nullptr);
  }

  // pre = cat_pre @ Wpre -> bf16 [NROW][H]
  gemm_bf16<64,0><<<dim3(NROW/64, H/64),256,0,stream>>>(
      catp, KP, wpreT, KP, KP, preb, H,
      nullptr,nullptr,nullptr,nullptr,nullptr,nullptr,nullptr,0,nullptr,nullptr,nullptr);

  // generator pass 1: sum-exp partials
  gemm_bf16<128,2><<<dim3(NROW/64, VP/128),256,0,stream>>>(
      preb, H, wgt, H, H, nullptr, 0,
      nullptr,nullptr,nullptr,nullptr,nullptr,nullptr,nullptr,0, sep, nullptr, nullptr);
  k_lse<<<cdiv(NROW,256),256,0,stream>>>(sep, lse);
  // generator pass 2: write out[b][v][t] = logit - lse
  gemm_bf16<128,3><<<dim3(NROW/64, VP/128),256,0,stream>>>(
      preb, H, wgt, H, H, nullptr, 0,
      nullptr,nullptr,nullptr,nullptr,nullptr,nullptr,nullptr,0, nullptr, out, lse);

  k_fin<<<cdiv(B*H,256),256,0,stream>>>(hfin, cbuf, out);
}

// Round 2
// 3353.084 us; speedup vs baseline: 1.3077x; 1.3077x over previous
//
#include <hip/hip_runtime.h>

#define B 64
#define S 128
#define T 64
#define H 512
#define E 256
#define V 10000
#define H2 1024      // 2H
#define G4 2048      // 4H
#define KX 1536      // ctx(1024)+h(512) gate GEMM K
#define KP 1792      // E + H + 2H pre concat K
#define VP 10112     // padded V = 79*128
#define NROW 4096    // B*T

typedef unsigned short u16;
typedef __attribute__((ext_vector_type(8))) short bf16x8;
typedef __attribute__((ext_vector_type(4))) float floatx4;

__device__ inline float b2f(u16 h){
  union { unsigned int u; float f; } v; v.u = ((unsigned int)h) << 16; return v.f;
}
__device__ inline u16 f2b(float f){
  union { unsigned int u; float f; } v; v.f = f;
  unsigned int r = v.u + 0x7FFFu + ((v.u >> 16) & 1u);
  return (u16)(r >> 16);
}
__device__ inline float sigf(float x){ return 1.f/(1.f+__expf(-x)); }
__device__ inline float tanh_fast(float x){ float e=__expf(2.f*x); return 1.f - 2.f/(e+1.f); }

// ---------------- prep kernels ----------------
__global__ void k_cast(const float* __restrict__ src, u16* __restrict__ dst, int n){
  int i = blockIdx.x*256 + threadIdx.x;
  if (i < n) dst[i] = f2b(src[i]);
}
// tiled transpose-cast: src fp32 [R][C] -> dst bf16 [Cpad][R], rows c>=C zeroed
__global__ void k_tct(const float* __restrict__ src, u16* __restrict__ dst, int R, int C){
  __shared__ float tile[64][65];
  int c0 = blockIdx.x*64, r0 = blockIdx.y*64;
  int tid = threadIdx.x;
  #pragma unroll
  for (int i=0;i<16;i++){
    int flat = i*256 + tid;
    int rr = flat >> 6, cc = flat & 63;
    int c = c0 + cc;
    tile[rr][cc] = (c < C) ? src[(size_t)(r0+rr)*C + c] : 0.f;
  }
  __syncthreads();
  #pragma unroll
  for (int i=0;i<16;i++){
    int flat = i*256 + tid;
    int cc = flat >> 6, rr = flat & 63;
    dst[(size_t)(c0+cc)*R + r0 + rr] = f2b(tile[rr][cc]);
  }
}
// Wch[gp][k]: gp = j*4+gate (permuted), k<1024 -> W_ih[g][E+k], else W_hh[g][k-1024]
__global__ void k_wch(const float* __restrict__ wih, const float* __restrict__ whh, u16* __restrict__ o){
  int i = blockIdx.x*256 + threadIdx.x;
  if (i < G4*KX){
    int gp = i / KX, k = i % KX;
    int j = gp >> 2, gate = gp & 3, g = gate*H + j;
    float v = (k < H2) ? wih[(size_t)g*(E+H2) + E + k] : whh[(size_t)g*H + (k - H2)];
    o[i] = f2b(v);
  }
}
__global__ void k_wihe(const float* __restrict__ wih, u16* __restrict__ o){
  int i = blockIdx.x*256 + threadIdx.x;
  if (i < G4*E){
    int gp = i / E, e = i % E;
    int j = gp >> 2, gate = gp & 3, g = gate*H + j;
    o[i] = f2b(wih[(size_t)g*(E+H2) + e]);
  }
}
__global__ void k_bias(const float* __restrict__ bi, const float* __restrict__ bh, float* __restrict__ o){
  int i = blockIdx.x*256 + threadIdx.x;
  if (i < G4){
    int j = i >> 2, gate = i & 3, g = gate*H + j;
    o[i] = bi[g] + bh[g];
  }
}
__global__ void k_emb(const int* __restrict__ trg, const float* __restrict__ emb, u16* __restrict__ catp){
  int i = blockIdx.x*256 + threadIdx.x;
  if (i < NROW*E){
    int row = i >> 8, e = i & 255;
    int tok = trg[row];
    catp[(size_t)row*KP + e] = f2b(emb[(size_t)tok*E + e]);
  }
}
__global__ void k_init(const float* __restrict__ h0, const float* __restrict__ c0,
                       u16* __restrict__ xg0, float* __restrict__ cb0){
  int i = blockIdx.x*256 + threadIdx.x;
  if (i < B*H){
    int b = i >> 9, j = i & 511;
    xg0[b*KX + H2 + j] = f2b(h0[i]);
    cb0[i] = c0[i];
  }
}
__global__ void k_lse(const float* __restrict__ sep, float* __restrict__ lse){
  int r = blockIdx.x*256 + threadIdx.x;
  if (r < NROW){
    float s = 0.f;
    for (int i=0;i<79;i++) s += sep[(size_t)r*80 + i];
    lse[r] = logf(s);
  }
}
__global__ void k_fin(const float* __restrict__ hf, const float* __restrict__ cf, float* __restrict__ out){
  int i = blockIdx.x*256 + threadIdx.x;
  if (i < B*H){
    out[(size_t)B*V*T + i] = hf[i];
    out[(size_t)B*V*T + B*H + i] = cf[i];
  }
}

// ---------------- MFMA GEMM: C[row,col] = sum_k A[row,k]*BT[col,k] ----------------
// rows tiled 64 (4 waves x 16), cols tiled TN. 256 threads. Swizzled LDS + reg prefetch.
// EPI 0: store bf16 C. EPI 2: sum-exp partials. EPI 3: out write with lse.
template<int TN, int EPI>
__global__ __launch_bounds__(256) void gemm_bf16(
    const u16* __restrict__ A, int lda,
    const u16* __restrict__ BT, int ldb,
    int K,
    u16* outb, int ldc,
    float* sep,
    float* outp, const float* lse)
{
  constexpr int NSUB = TN/16;
  constexpr int NB = TN/64;
  __shared__ u16 sA[64*32];
  __shared__ u16 sB[TN*32];
  __shared__ float Cx[(EPI==3) ? 128*65 : 1];
  __shared__ float lseb[(EPI==3)?64:1];

  const int tid = threadIdx.x;
  const int lane = tid & 63;
  const int wv = tid >> 6;
  const int row0 = blockIdx.x * 64;
  const int n0 = blockIdx.y * TN;

  floatx4 acc[NSUB];
  #pragma unroll
  for (int s=0;s<NSUB;s++) acc[s] = (floatx4){0.f,0.f,0.f,0.f};

  const int ar = tid >> 2;          // staging row 0..63
  const int ch = tid & 3;           // staging chunk 0..3 (8 elems)
  const int swz = (ar >> 1) & 3;    // row-based chunk swizzle
  const int px = ((lane & 15) >> 1) & 3;  // read-side swizzle

  const u16* gA = A + (size_t)(row0+ar)*lda + ch*8;
  bf16x8 pa = *(const bf16x8*)gA;
  bf16x8 pb[NB];
  #pragma unroll
  for (int i=0;i<NB;i++) pb[i] = *(const bf16x8*)(BT + (size_t)(n0+i*64+ar)*ldb + ch*8);

  for (int k0 = 0; k0 < K; k0 += 32){
    __syncthreads();
    *(bf16x8*)&sA[ar*32 + ((ch ^ swz)*8)] = pa;
    #pragma unroll
    for (int i=0;i<NB;i++)
      *(bf16x8*)&sB[(i*64+ar)*32 + ((ch ^ swz)*8)] = pb[i];
    __syncthreads();
    if (k0 + 32 < K){
      pa = *(const bf16x8*)(gA + k0 + 32);
      #pragma unroll
      for (int i=0;i<NB;i++) pb[i] = *(const bf16x8*)(BT + (size_t)(n0+i*64+ar)*ldb + k0+32 + ch*8);
    }
    bf16x8 af = *(const bf16x8*)&sA[(16*wv + (lane&15))*32 + (((lane>>4) ^ px)*8)];
    #pragma unroll
    for (int s=0;s<NSUB;s++){
      bf16x8 bfv = *(const bf16x8*)&sB[(16*s + (lane&15))*32 + (((lane>>4) ^ px)*8)];
      acc[s] = __builtin_amdgcn_mfma_f32_16x16x32_bf16(af, bfv, acc[s], 0, 0, 0);
    }
  }

  if constexpr (EPI == 0){
    #pragma unroll
    for (int s=0;s<NSUB;s++)
      #pragma unroll
      for (int r=0;r<4;r++){
        int row = row0 + 16*wv + ((lane>>4)<<2) + r;
        int col = n0 + 16*s + (lane&15);
        outb[(size_t)row*ldc + col] = f2b(acc[s][r]);
      }
  }
  if constexpr (EPI == 2){
    float sr[4] = {0.f,0.f,0.f,0.f};
    #pragma unroll
    for (int s=0;s<NSUB;s++){
      int col = n0 + 16*s + (lane&15);
      if (col < V){
        #pragma unroll
        for (int r=0;r<4;r++) sr[r] += __expf(acc[s][r]);
      }
    }
    #pragma unroll
    for (int r=0;r<4;r++){
      float v = sr[r];
      v += __shfl_xor(v,1); v += __shfl_xor(v,2); v += __shfl_xor(v,4); v += __shfl_xor(v,8);
      sr[r] = v;
    }
    if ((lane&15)==0){
      #pragma unroll
      for (int r=0;r<4;r++){
        int row = row0 + 16*wv + ((lane>>4)<<2) + r;
        sep[(size_t)row*80 + blockIdx.y] = sr[r];
      }
    }
  }
  if constexpr (EPI == 3){
    #pragma unroll
    for (int s=0;s<NSUB;s++)
      #pragma unroll
      for (int r=0;r<4;r++){
        int rl = 16*wv + ((lane>>4)<<2) + r;   // t within row-block (row = b*T+t, block covers one b)
        int cl = 16*s + (lane&15);             // v local
        Cx[cl*65 + rl] = acc[s][r];
      }
    if (tid < 64) lseb[tid] = lse[row0 + tid];
    __syncthreads();
    int b = blockIdx.x;
    for (int idx = tid; idx < TN*16; idx += 256){
      int vl = idx >> 4, q4 = idx & 15;
      int v = n0 + vl;
      if (v < V){
        floatx4 o;
        o[0] = Cx[vl*65 + q4*4+0] - lseb[q4*4+0];
        o[1] = Cx[vl*65 + q4*4+1] - lseb[q4*4+1];
        o[2] = Cx[vl*65 + q4*4+2] - lseb[q4*4+2];
        o[3] = Cx[vl*65 + q4*4+3] - lseb[q4*4+3];
        *(floatx4*)&outp[((size_t)b*V + v)*T + q4*4] = o;
      }
    }
  }
}

// ---------------- per-step gates GEMM + LSTM pointwise ----------------
// grid (32), 512 threads = 8 waves. Split-K: waves 0-3 low 64k, 4-7 high 64k of each BK=128 tile.
__global__ __launch_bounds__(512) void step_gemm(
    const u16* __restrict__ xgc,   // A [64][KX]
    const u16* __restrict__ wch,   // BT [2048][KX]
    const u16* __restrict__ gemb, const float* __restrict__ bias,
    const float* __restrict__ cin, float* __restrict__ cout,
    float* __restrict__ hfin, u16* __restrict__ xgn, u16* __restrict__ cph, int t)
{
  __shared__ u16 sA[64*128];
  __shared__ u16 sB[64*128];
  __shared__ float Cx[64*68];
  const int tid = threadIdx.x, lane = tid & 63, wv = tid >> 6;
  const int n0 = blockIdx.x * 64;
  const int kh = wv >> 2, wr = wv & 3;

  floatx4 acc[4];
  #pragma unroll
  for (int s=0;s<4;s++) acc[s] = (floatx4){0.f,0.f,0.f,0.f};

  const int rs0 = tid >> 4, gs = tid & 15;   // staging: 2 chunks/thread
  const int rs1 = rs0 + 32;

  bf16x8 a0 = *(const bf16x8*)(xgc + (size_t)rs0*KX + gs*8);
  bf16x8 a1 = *(const bf16x8*)(xgc + (size_t)rs1*KX + gs*8);
  bf16x8 b0 = *(const bf16x8*)(wch + (size_t)(n0+rs0)*KX + gs*8);
  bf16x8 b1 = *(const bf16x8*)(wch + (size_t)(n0+rs1)*KX + gs*8);

  const int rowa = 16*wr + (lane & 15);

  for (int kk = 0; kk < 12; kk++){
    __syncthreads();
    *(bf16x8*)&sA[rs0*128 + ((gs ^ (rs0&7))*8)] = a0;
    *(bf16x8*)&sA[rs1*128 + ((gs ^ (rs1&7))*8)] = a1;
    *(bf16x8*)&sB[rs0*128 + ((gs ^ (rs0&7))*8)] = b0;
    *(bf16x8*)&sB[rs1*128 + ((gs ^ (rs1&7))*8)] = b1;
    __syncthreads();
    if (kk < 11){
      int ko = (kk+1)*128;
      a0 = *(const bf16x8*)(xgc + (size_t)rs0*KX + ko + gs*8);
      a1 = *(const bf16x8*)(xgc + (size_t)rs1*KX + ko + gs*8);
      b0 = *(const bf16x8*)(wch + (size_t)(n0+rs0)*KX + ko + gs*8);
      b1 = *(const bf16x8*)(wch + (size_t)(n0+rs1)*KX + ko + gs*8);
    }
    #pragma unroll
    for (int ks=0; ks<2; ks++){
      int gq = kh*8 + ks*4 + (lane>>4);
      bf16x8 af = *(const bf16x8*)&sA[rowa*128 + ((gq ^ (rowa&7))*8)];
      #pragma unroll
      for (int s=0;s<4;s++){
        int rowb = 16*s + (lane & 15);
        bf16x8 bfv = *(const bf16x8*)&sB[rowb*128 + ((gq ^ (rowb&7))*8)];
        acc[s] = __builtin_amdgcn_mfma_f32_16x16x32_bf16(af, bfv, acc[s], 0, 0, 0);
      }
    }
  }

  // combine K-halves in LDS
  const int rbase = 16*wr + ((lane>>4)<<2);
  if (kh == 1){
    #pragma unroll
    for (int s=0;s<4;s++)
      #pragma unroll
      for (int r=0;r<4;r++)
        Cx[(rbase+r)*68 + 16*s + (lane&15)] = acc[s][r];
  }
  __syncthreads();
  if (kh == 0){
    #pragma unroll
    for (int s=0;s<4;s++)
      #pragma unroll
      for (int r=0;r<4;r++){
        int ix = (rbase+r)*68 + 16*s + (lane&15);
        Cx[ix] += acc[s][r];
      }
  }
  __syncthreads();

  // LSTM pointwise: 64 b x 16 j per block
  #pragma unroll
  for (int it=0; it<2; it++){
    int idx = tid + it*512;
    int b = idx >> 4, jl = idx & 15;
    int gp = n0 + jl*4;
    int j = (n0 >> 2) + jl;
    size_t grow = (size_t)(b*T + t)*G4 + gp;
    float gi = Cx[b*68 + jl*4+0] + b2f(gemb[grow+0]) + bias[gp+0];
    float gf = Cx[b*68 + jl*4+1] + b2f(gemb[grow+1]) + bias[gp+1];
    float gg = Cx[b*68 + jl*4+2] + b2f(gemb[grow+2]) + bias[gp+2];
    float go = Cx[b*68 + jl*4+3] + b2f(gemb[grow+3]) + bias[gp+3];
    float cold = cin[b*H + j];
    float cn = sigf(gf)*cold + sigf(gi)*tanhf(gg);
    float hn = sigf(go)*tanhf(cn);
    cout[b*H + j] = cn;
    hfin[b*H + j] = hn;
    u16 hb = f2b(hn);
    xgn[b*KX + H2 + j] = hb;
    cph[(size_t)(b*T + t)*KP + E + j] = hb;
  }
}

// ---------------- per-step attention (one block per batch element) ----------------
__global__ __launch_bounds__(512) void attn_step(
    u16* __restrict__ xg,          // read h at [b][H2..], write ctx at [b][0..H2)
    const u16* __restrict__ pk,    // [B*S][H] bf16
    const u16* __restrict__ encb,  // [B*S][H2] bf16
    const float* __restrict__ we,
    const int* __restrict__ lens,
    const u16* __restrict__ wqb,   // [H][H] bf16, original [k][j] layout
    u16* __restrict__ cph,
    int t)
{
  __shared__ float hsh[H], qw[H], wel[H];
  __shared__ float ep[512];
  __shared__ float ev[S], al[S];
  __shared__ float smax, sinv;
  const int tid = threadIdx.x;
  const int b = blockIdx.x;

  hsh[tid] = b2f(xg[b*KX + H2 + tid]);
  wel[tid] = we[tid];
  __syncthreads();

  // q[j] = sum_k h[k] * Wquery[k][j] — column reads, coalesced across lanes
  {
    float a0 = 0.f;
    const u16* wc = wqb + tid;
    for (int k=0;k<H;k+=4){
      a0 += hsh[k+0]*b2f(wc[(size_t)(k+0)*H]);
      a0 += hsh[k+1]*b2f(wc[(size_t)(k+1)*H]);
      a0 += hsh[k+2]*b2f(wc[(size_t)(k+2)*H]);
      a0 += hsh[k+3]*b2f(wc[(size_t)(k+3)*H]);
    }
    qw[tid] = a0;
  }
  __syncthreads();

  // energies: 4 threads per s; 4 lanes of one s cover one 64B line per step
  {
    int s = tid >> 2, part = tid & 3;
    const u16* pr = pk + (size_t)(b*S + s)*H;
    float a0 = 0.f;
    #pragma unroll 4
    for (int m=0;m<16;m++){
      int k0 = part*8 + m*32;
      bf16x8 p8 = *(const bf16x8*)(pr + k0);
      #pragma unroll
      for (int i=0;i<8;i++){
        float x = qw[k0+i] + b2f((u16)p8[i]);
        a0 += tanh_fast(x) * wel[k0+i];
      }
    }
    ep[tid] = a0;
  }
  __syncthreads();
  if (tid < S){
    float e = ep[tid*4] + ep[tid*4+1] + ep[tid*4+2] + ep[tid*4+3];
    ev[tid] = (tid < lens[b]) ? e : -1e30f;
  }
  __syncthreads();
  if (tid < 64){
    float m = fmaxf(ev[tid], ev[tid+64]);
    #pragma unroll
    for (int o=32;o>=1;o>>=1) m = fmaxf(m, __shfl_xor(m,o));
    if (tid==0) smax = m;
  }
  __syncthreads();
  if (tid < S) al[tid] = __expf(ev[tid]-smax);
  __syncthreads();
  if (tid < 64){
    float s2 = al[tid] + al[tid+64];
    #pragma unroll
    for (int o=32;o>=1;o>>=1) s2 += __shfl_xor(s2,o);
    if (tid==0) sinv = 1.f/s2;
  }
  __syncthreads();

  // ctx: 2 dims per thread
  {
    float c0=0.f, c1=0.f;
    int d = tid*2;
    const u16* er = encb + (size_t)(b*S)*H2 + d;
    for (int ss=0; ss<S; ss++){
      unsigned int u = *(const unsigned int*)(er + (size_t)ss*H2);
      float a = al[ss];
      c0 += a * b2f((u16)(u & 0xFFFFu));
      c1 += a * b2f((u16)(u >> 16));
    }
    c0 *= sinv; c1 *= sinv;
    u16 h0b = f2b(c0), h1b = f2b(c1);
    xg[b*KX + d] = h0b; xg[b*KX + d + 1] = h1b;
    size_t cr = (size_t)(b*T + t)*KP + E + H + d;
    cph[cr] = h0b; cph[cr+1] = h1b;
  }
}

static inline int cdiv(int a, int b){ return (a + b - 1) / b; }

extern "C" void kernel_launch(void* const* d_in, const int* in_sizes, int n_in,
                              void* d_out, int out_size, void* d_ws, size_t ws_size,
                              hipStream_t stream)
{
  (void)in_sizes; (void)n_in; (void)out_size; (void)ws_size;
  const int*   trg  = (const int*)d_in[0];
  const float* enc  = (const float*)d_in[1];
  const int*   lens = (const int*)d_in[2];
  const float* h0   = (const float*)d_in[3];
  const float* c0   = (const float*)d_in[4];
  const float* embt = (const float*)d_in[5];
  const float* wkey = (const float*)d_in[6];
  const float* wqry = (const float*)d_in[7];
  const float* we   = (const float*)d_in[8];
  const float* wih  = (const float*)d_in[9];
  const float* whh  = (const float*)d_in[10];
  const float* bi   = (const float*)d_in[11];
  const float* bh   = (const float*)d_in[12];
  const float* wpre = (const float*)d_in[13];
  const float* wgen = (const float*)d_in[14];
  float* out = (float*)d_out;

  char* p = (char*)d_ws;
  auto carve = [&](size_t bytes)->char*{ char* r = p; p += (bytes + 255) & ~(size_t)255; return r; };
  u16*   encb  = (u16*)  carve((size_t)B*S*H2*2);
  u16*   pkb   = (u16*)  carve((size_t)B*S*H*2);
  u16*   catp  = (u16*)  carve((size_t)NROW*KP*2);
  u16*   gembb = (u16*)  carve((size_t)NROW*G4*2);
  u16*   preb  = (u16*)  carve((size_t)NROW*H*2);
  u16*   wgt   = (u16*)  carve((size_t)VP*H*2);
  u16*   wch   = (u16*)  carve((size_t)G4*KX*2);
  u16*   wihe  = (u16*)  carve((size_t)G4*E*2);
  u16*   wkeyT = (u16*)  carve((size_t)H*H2*2);
  u16*   wqb   = (u16*)  carve((size_t)H*H*2);
  u16*   wpreT = (u16*)  carve((size_t)H*KP*2);
  u16*   xg    = (u16*)  carve((size_t)2*B*KX*2);
  float* cbuf  = (float*)carve((size_t)2*B*H*4);
  float* hfin  = (float*)carve((size_t)B*H*4);
  float* biasp = (float*)carve((size_t)G4*4);
  float* sep   = (float*)carve((size_t)NROW*80*4);
  float* lse   = (float*)carve((size_t)NROW*4);

  // ---- prep ----
  k_cast<<<cdiv(B*S*H2,256),256,0,stream>>>(enc, encb, B*S*H2);
  k_cast<<<cdiv(H*H,256),256,0,stream>>>(wqry, wqb, H*H);
  k_tct<<<dim3(H/64, H2/64),256,0,stream>>>(wkey, wkeyT, H2, H);     // -> [H][H2]
  k_tct<<<dim3(H/64, KP/64),256,0,stream>>>(wpre, wpreT, KP, H);     // -> [H][KP]
  k_tct<<<dim3(VP/64, H/64),256,0,stream>>>(wgen, wgt, H, V);        // -> [VP][H]
  k_wch<<<cdiv(G4*KX,256),256,0,stream>>>(wih, whh, wch);
  k_wihe<<<cdiv(G4*E,256),256,0,stream>>>(wih, wihe);
  k_bias<<<cdiv(G4,256),256,0,stream>>>(bi, bh, biasp);
  k_emb<<<cdiv(NROW*E,256),256,0,stream>>>(trg, embt, catp);
  k_init<<<cdiv(B*H,256),256,0,stream>>>(h0, c0, xg, cbuf);

  // proj_key = enc @ Wkey  -> pk bf16 [B*S][H]
  gemm_bf16<64,0><<<dim3(B*S/64, H/64),256,0,stream>>>(
      encb, H2, wkeyT, H2, H2, pkb, H, nullptr, nullptr, nullptr);
  // Gemb = emb @ W_ih[:, :E].T (permuted cols) -> bf16 [NROW][G4]
  gemm_bf16<64,0><<<dim3(NROW/64, G4/64),256,0,stream>>>(
      catp, KP, wihe, E, E, gembb, G4, nullptr, nullptr, nullptr);

  // ---- recurrence ----
  for (int t=0; t<T; t++){
    u16* xgc = xg + (size_t)(t&1)*B*KX;
    u16* xgn = xg + (size_t)((t+1)&1)*B*KX;
    float* cin_  = cbuf + (size_t)(t&1)*B*H;
    float* cout_ = cbuf + (size_t)((t+1)&1)*B*H;
    attn_step<<<B,512,0,stream>>>(xgc, pkb, encb, we, lens, wqb, catp, t);
    step_gemm<<<G4/64,512,0,stream>>>(xgc, wch, gembb, biasp, cin_, cout_, hfin, xgn, catp, t);
  }

  // pre = cat_pre @ Wpre -> bf16 [NROW][H]
  gemm_bf16<64,0><<<dim3(NROW/64, H/64),256,0,stream>>>(
      catp, KP, wpreT, KP, KP, preb, H, nullptr, nullptr, nullptr);

  // generator pass 1: sum-exp partials
  gemm_bf16<128,2><<<dim3(NROW/64, VP/128),256,0,stream>>>(
      preb, H, wgt, H, H, nullptr, 0, sep, nullptr, nullptr);
  k_lse<<<cdiv(NROW,256),256,0,stream>>>(sep, lse);
  // generator pass 2: write out[b][v][t] = logit - lse
  gemm_bf16<128,3><<<dim3(NROW/64, VP/128),256,0,stream>>>(
      preb, H, wgt, H, H, nullptr, 0, nullptr, out, lse);

  k_fin<<<cdiv(B*H,256),256,0,stream>>>(hfin, cbuf, out);
}